// Round 7
// baseline (111.943 us; speedup 1.0000x reference)
//
#include <hip/hip_runtime.h>
#include <math.h>

#define NB     16      // batches
#define NP     4096    // points per cloud (N == M)
#define BLK    1024    // 16 waves
#define NWAVE  16
#define ILP    8       // x-points per lane -> one LDS read feeds 56 VALU ops
#define XPB    (64 * ILP)     // 512 x-points per block (every wave holds all)
#define CHUNK  1024    // y-points staged in LDS per chunk (16 KB)
#define YHALF  (NP / 2)       // each block covers half of M (2 chunks)
#define YQ     (CHUNK / NWAVE)  // 64 y per wave per chunk

// R6 post-mortem: 48us at "98% VALUBusy" vs 27us 4-op floor -- the derived
// counter uses gfx94x SIMD-16 formulas (x2 inflation on SIMD-32); real binder
// is latency at 16 waves/CU with one block stalling whole-CU at each barrier.
// Now: 2 blocks/CU (y-range halved, combined via uint atomicMin), and the
// inner loop pairs 2 y per mx update: 6 FMA + 1 max3 = 3.5 VALU/pair.
__global__ __launch_bounds__(BLK, 8) void chamfer_kernel(
    const float* __restrict__ A1, const float* __restrict__ A2,
    unsigned int* __restrict__ minbits)
{
    __shared__ float4 sy[CHUNK];   // 16 KB; 2 blocks/CU -> 32 KB
    const int b   = blockIdx.x;    // batch
    const int xc  = blockIdx.y;    // x-chunk (NP/XPB = 8)
    const int z   = blockIdx.z;    // bit0: y-half, bit1: direction
    const int yh  = z & 1;
    const int dir = z >> 1;
    const float* X = dir ? A2 : A1;
    const float* Y = dir ? A1 : A2;

    const int tid  = threadIdx.x;
    const int lane = tid & 63;
    const int w    = tid >> 6;     // 0..15

    // My 8 x-points (lanes contiguous within each p -> coalesced 12 B/lane).
    const float* Xb = X + ((size_t)b * NP + xc * XPB) * 3;
    float px[ILP], py[ILP], pz[ILP], ax[ILP], mx[ILP];
    #pragma unroll
    for (int p = 0; p < ILP; ++p) {
        const int n = p * 64 + lane;
        px[p] = Xb[n * 3 + 0];
        py[p] = Xb[n * 3 + 1];
        pz[p] = Xb[n * 3 + 2];
        ax[p] = 0.5f * (px[p] * px[p] + py[p] * py[p] + pz[p] * pz[p]);
        mx[p] = -3.3e38f;
    }

    const float* Yb = Y + ((size_t)b * NP + yh * YHALF) * 3;
    for (int c = 0; c < YHALF / CHUNK; ++c) {
        __syncthreads();   // previous chunk fully consumed
        {
            const int i = tid;  // 1024 threads stage 1024 y
            const float* yp = Yb + (size_t)(c * CHUNK + i) * 3;
            const float yx = yp[0], yy = yp[1], yz = yp[2];
            sy[i] = make_float4(yx, yy, yz, -0.5f * (yx * yx + yy * yy + yz * yz));
        }
        __syncthreads();

        const float4* syq = sy + w * YQ;   // this wave's sixteenth
        #pragma unroll 4
        for (int j = 0; j < YQ; j += 2) {
            const float4 y0 = syq[j];
            const float4 y1 = syq[j + 1];
            #pragma unroll
            for (int p = 0; p < ILP; ++p) {
                float m0 = fmaf(pz[p], y0.z, y0.w);
                m0 = fmaf(py[p], y0.y, m0);
                m0 = fmaf(px[p], y0.x, m0);
                float m1 = fmaf(pz[p], y1.z, y1.w);
                m1 = fmaf(py[p], y1.y, m1);
                m1 = fmaf(px[p], y1.x, m1);
                mx[p] = fmaxf(fmaxf(mx[p], m0), m1);   // -> v_max3_f32
            }
        }
    }

    // Tree-combine 16 wave-partials (reusing sy), then one atomicMin per x.
    __syncthreads();
    float* sbuf = (float*)sy;
    for (int half = NWAVE / 2; half >= 1; half >>= 1) {
        if (w >= half && w < 2 * half) {
            #pragma unroll
            for (int p = 0; p < ILP; ++p)
                sbuf[(w - half) * XPB + p * 64 + lane] = mx[p];
        }
        __syncthreads();
        if (w < half) {
            #pragma unroll
            for (int p = 0; p < ILP; ++p)
                mx[p] = fmaxf(mx[p], sbuf[w * XPB + p * 64 + lane]);
        }
        __syncthreads();
    }

    if (w == 0) {   // wave 0 holds the block max over this y-half
        unsigned int* mb = minbits + ((size_t)dir * NB + b) * NP + xc * XPB;
        #pragma unroll
        for (int p = 0; p < ILP; ++p) {
            const float e = fmaxf(ax[p] - mx[p], 0.0f);   // = d_min/2 (this half)
            atomicMin(&mb[p * 64 + lane], __float_as_uint(e));  // coalesced
        }
    }
}

// Single block: uint4 grid-stride over 128K mins, sqrt(2e), reduce, write out.
__global__ __launch_bounds__(1024) void reduce_kernel(
    const unsigned int* __restrict__ minbits, float* __restrict__ out)
{
    const uint4* mb4 = (const uint4*)minbits;
    float s = 0.0f;
    for (int i = threadIdx.x; i < (2 * NB * NP) / 4; i += 1024) {
        const uint4 u = mb4[i];
        s += sqrtf(2.0f * __uint_as_float(u.x)) + sqrtf(2.0f * __uint_as_float(u.y))
           + sqrtf(2.0f * __uint_as_float(u.z)) + sqrtf(2.0f * __uint_as_float(u.w));
    }
    #pragma unroll
    for (int off = 32; off > 0; off >>= 1)
        s += __shfl_down(s, off, 64);

    __shared__ float ws[16];
    const int lane = threadIdx.x & 63;
    const int wid  = threadIdx.x >> 6;
    if (lane == 0) ws[wid] = s;
    __syncthreads();
    if (threadIdx.x == 0) {
        float t = 0.0f;
        #pragma unroll
        for (int v = 0; v < 16; ++v) t += ws[v];
        // out = (sum1+sum2) * 1000 / (2 * NB * NP); 1000/131072 exact in fp32.
        out[0] = t * 0.00762939453125f;
    }
}

extern "C" void kernel_launch(void* const* d_in, const int* in_sizes, int n_in,
                              void* d_out, int out_size, void* d_ws, size_t ws_size,
                              hipStream_t stream)
{
    const float* a1 = (const float*)d_in[0];  // [NB, NP, 3] fp32
    const float* a2 = (const float*)d_in[1];  // [NB, NP, 3] fp32
    float* out = (float*)d_out;
    unsigned int* minbits = (unsigned int*)d_ws;   // [2, NB, NP]

    // 0x7F7F7F7F ~ 3.39e38f > any clamped e; uint order == float order (e>=0).
    hipMemsetAsync(minbits, 0x7F, (size_t)2 * NB * NP * sizeof(unsigned int), stream);

    dim3 grid(NB, NP / XPB, 4);   // 16 x 8 x (2 y-half * 2 dir) = 512 blocks = 2/CU
    chamfer_kernel<<<grid, BLK, 0, stream>>>(a1, a2, minbits);

    reduce_kernel<<<1, 1024, 0, stream>>>(minbits, out);
}